// Round 3
// baseline (606.815 us; speedup 1.0000x reference)
//
#include <hip/hip_runtime.h>

// positional_spiking_attention, T=4 B=4 L=1024 D=512, window=8.
// Round 3: fix k_lif_first OOB (round-2 crash). bf16 MFMA GEMMs with exact
// 2-split weights (w ~= hi+mid, residual <= 2^-17|w|), LIF+BN fused into GEMM
// epilogue, boundary columns (|m-0.5| < 1e-3) recomputed bitwise-np-exactly
// (sequential-k fp32 fma) by k_fixup.
//
// ws layout (bytes):
//   0        : xs  bf16 [4][4096][512] first_lif spikes  (16 MB)
//   16 MB    : qs  bf16 q spikes
//   32 MB    : kv  bf16 k*v spikes
//   48 MB    : as_ bf16 attn_lif spikes
//   64 MB    : weight splits bf16 [k,v,q,last] x [hi,mid,lo] x 262144  (6 MB)
//   70 MB    : worklist counter (4 B) ; +16 B: worklist entries (1 MB)

#define Tt 4
#define BL 4096
#define Dd 512
#define TSTRIDE (BL*Dd)      // 2097152 elements per time step
#define WELEM (Dd*Dd)        // 262144
#define INV_STD 0.9999950000374997f
#define MARGIN 1e-3f
#define WL_CAP 262144u

typedef __attribute__((ext_vector_type(8))) short short8;
typedef __attribute__((ext_vector_type(4))) float floatx4;

#define ASG __attribute__((address_space(1)))
#define ASL __attribute__((address_space(3)))

static __device__ __forceinline__ void gl2lds16(const void* g, void* l) {
  __builtin_amdgcn_global_load_lds((ASG const unsigned int*)g, (ASL unsigned int*)l, 16, 0, 0);
}

static __device__ __forceinline__ unsigned short f2bf(float f) {
  union { float f; unsigned int u; } v; v.f = f;
  unsigned int u = v.u;
  return (unsigned short)((u + 0x7fffu + ((u >> 16) & 1u)) >> 16);
}
static __device__ __forceinline__ float bf2f(unsigned short h) {
  union { unsigned int u; float f; } v; v.u = ((unsigned int)h) << 16;
  return v.f;
}
static __device__ __forceinline__ void unpack8(uint4 r, float* f) {
  const unsigned int u[4] = {r.x, r.y, r.z, r.w};
#pragma unroll
  for (int j = 0; j < 4; ++j) {
    union { unsigned int i; float f; } a, b;
    a.i = u[j] << 16;
    b.i = u[j] & 0xFFFF0000u;
    f[2 * j] = a.f;
    f[2 * j + 1] = b.f;
  }
}

// ---------------- weight split prep: w = hi + mid (+lo unused) ----------------
__global__ __launch_bounds__(256) void k_prep_w(const float* __restrict__ qw,
                                                const float* __restrict__ kw,
                                                const float* __restrict__ vw,
                                                const float* __restrict__ lw,
                                                unsigned short* __restrict__ wsp) {
  const int e = blockIdx.x * 256 + threadIdx.x;  // 0..262143
  const float* srcs[4] = {kw, vw, qw, lw};       // gemm pass order: k, v, q, last
#pragma unroll
  for (int m2 = 0; m2 < 4; ++m2) {
    const float w = srcs[m2][e];
    const unsigned short hi = f2bf(w);
    const float r1 = w - bf2f(hi);
    const unsigned short mid = f2bf(r1);
    const float r2 = r1 - bf2f(mid);
    const unsigned short lo = f2bf(r2);
    unsigned short* dst = wsp + (size_t)m2 * 3 * WELEM + e;
    dst[0] = hi;
    dst[WELEM] = mid;
    dst[2 * WELEM] = lo;
  }
}

// ---------------- first LIF: x fp32 -> xs spikes bf16 ----------------
// 262144 threads (1024 blocks); each thread: 8 channels, all 4 t.
__global__ __launch_bounds__(256) void k_lif_first(const float* __restrict__ x,
                                                   unsigned short* __restrict__ xs,
                                                   unsigned int* __restrict__ cnt) {
  const int idx = blockIdx.x * 256 + threadIdx.x;  // 0..262143
  if (blockIdx.x == 0 && threadIdx.x == 0) cnt[0] = 0u;
  const float4* x4 = (const float4*)x;
  uint4* o4 = (uint4*)xs;
  float m[8], s[8];
#pragma unroll
  for (int t = 0; t < Tt; ++t) {
    float4 a = x4[(size_t)t * 524288 + (size_t)idx * 2];
    float4 b = x4[(size_t)t * 524288 + (size_t)idx * 2 + 1];
    float xv[8] = {a.x, a.y, a.z, a.w, b.x, b.y, b.z, b.w};
    uint4 ow;
    unsigned short* owp = (unsigned short*)&ow;
#pragma unroll
    for (int c = 0; c < 8; ++c) {
      m[c] = (t == 0) ? xv[c] : m[c] * 0.25f * (1.0f - s[c]) + xv[c];
      s[c] = m[c] > 0.5f ? 1.0f : 0.0f;
      owp[c] = m[c] > 0.5f ? (unsigned short)0x3F80 : (unsigned short)0;
    }
    o4[(size_t)t * 262144 + idx] = ow;
  }
}

// ---------------- fused q/k/v GEMM + BN + LIF + boundary flagging ----------------
// A = xs bf16 [16384][512] (row = t*4096 + bl). Block: 128 cols x (32 bl x 4 t) rows.
// 4 waves split N; each wave holds all 8 m-tiles -> LIF chain over t is in-lane.
// 3 passes (k, v, q), each a dual-split bf16 MFMA GEMM over K=512.
__global__ __launch_bounds__(256) void k_qkv_fused(
    const unsigned short* __restrict__ A, const unsigned short* __restrict__ wsp,
    const float* __restrict__ k_b, const float* __restrict__ k_g, const float* __restrict__ k_be,
    const float* __restrict__ v_b, const float* __restrict__ v_g, const float* __restrict__ v_be,
    const float* __restrict__ q_b, const float* __restrict__ q_g, const float* __restrict__ q_be,
    unsigned short* __restrict__ qs_out, unsigned short* __restrict__ kv_out,
    unsigned int* __restrict__ cnt, unsigned int* __restrict__ wl) {
  __shared__ __align__(16) unsigned short Atile[128 * 32];
  __shared__ __align__(16) unsigned short Btile[2][128 * 32];
  const int tid = threadIdx.x;
  const int lane = tid & 63, wid = tid >> 6;
  const int quad = lane >> 4, lm = lane & 15;
  const int c0 = blockIdx.x * 128;
  const int bl0 = blockIdx.y * 32;
  const int rr = tid >> 2;         // staging row 0..63
  const int kc = (tid & 3) * 8;    // staging k-elem offset (shorts)

  unsigned long long kmask = 0ull;

  for (int p = 0; p < 3; ++p) {
    const unsigned short* Wb = wsp + (size_t)p * 3 * WELEM;
    const float* bias = p == 0 ? k_b : (p == 1 ? v_b : q_b);
    const float* gam  = p == 0 ? k_g : (p == 1 ? v_g : q_g);
    const float* bet  = p == 0 ? k_be : (p == 1 ? v_be : q_be);

    floatx4 acc[8][2];
#pragma unroll
    for (int mt = 0; mt < 8; ++mt)
#pragma unroll
      for (int nt = 0; nt < 2; ++nt) acc[mt][nt] = (floatx4)0.0f;

    for (int ks = 0; ks < 16; ++ks) {
      const int k0 = ks * 32;
      __syncthreads();
#pragma unroll
      for (int s = 0; s < 2; ++s) {
        const int l = s * 64 + rr;
        const int t = l >> 5, i = l & 31;
        gl2lds16(A + ((size_t)(t * BL + bl0 + i) * Dd + k0 + kc),
                 &Atile[s * 2048 + tid * 8]);
      }
#pragma unroll
      for (int sp = 0; sp < 2; ++sp)
#pragma unroll
        for (int s = 0; s < 2; ++s) {
          const int n = s * 64 + rr;
          gl2lds16(Wb + (size_t)sp * WELEM + (size_t)(c0 + n) * Dd + k0 + kc,
                   &Btile[sp][s * 2048 + tid * 8]);
        }
      __syncthreads();
      short8 af[8];
#pragma unroll
      for (int mt = 0; mt < 8; ++mt)
        af[mt] = *(const short8*)&Atile[(mt * 16 + lm) * 32 + quad * 8];
#pragma unroll
      for (int nt = 0; nt < 2; ++nt) {
        const int nrow = wid * 32 + nt * 16 + lm;
#pragma unroll
        for (int sp = 0; sp < 2; ++sp) {
          short8 bfr = *(const short8*)&Btile[sp][nrow * 32 + quad * 8];
#pragma unroll
          for (int mt = 0; mt < 8; ++mt)
            acc[mt][nt] = __builtin_amdgcn_mfma_f32_16x16x32_bf16(af[mt], bfr, acc[mt][nt], 0, 0, 0);
        }
      }
    }

    // epilogue: BN + LIF (chain over t = mt>>1 is in-lane), flag boundary cols
    float scl[2], sft[2];
#pragma unroll
    for (int nt = 0; nt < 2; ++nt) {
      const int c = c0 + wid * 32 + nt * 16 + lm;
      scl[nt] = INV_STD * gam[c];
      sft[nt] = bias[c] * scl[nt] + bet[c];
    }
#pragma unroll
    for (int hl = 0; hl < 2; ++hl)
#pragma unroll
      for (int nt = 0; nt < 2; ++nt)
#pragma unroll
        for (int r = 0; r < 4; ++r) {
          float m = 0.f, s = 0.f;
          bool near = false;
#pragma unroll
          for (int t = 0; t < 4; ++t) {
            const int mt = 2 * t + hl;
            const float y = acc[mt][nt][r] * scl[nt] + sft[nt];
            m = (t == 0) ? y : m * 0.25f * (1.0f - s) + y;
            s = m > 0.5f ? 1.0f : 0.0f;
            near |= fabsf(m - 0.5f) < MARGIN;
            const int bit = mt * 8 + nt * 4 + r;
            if (p == 0) {
              kmask |= ((unsigned long long)(m > 0.5f ? 1 : 0)) << bit;
            } else {
              const size_t row = (size_t)t * BL + bl0 + hl * 16 + quad * 4 + r;
              const size_t off = row * Dd + (c0 + wid * 32 + nt * 16 + lm);
              if (p == 1) {
                const unsigned int kb = (unsigned int)((kmask >> bit) & 1ull);
                kv_out[off] = (kb && m > 0.5f) ? (unsigned short)0x3F80 : (unsigned short)0;
              } else {
                qs_out[off] = (m > 0.5f) ? (unsigned short)0x3F80 : (unsigned short)0;
              }
            }
          }
          if (near) {
            const unsigned int bl = bl0 + hl * 16 + quad * 4 + r;
            const unsigned int c = c0 + wid * 32 + nt * 16 + lm;
            const unsigned int pos = atomicAdd(cnt, 1u);
            if (pos < WL_CAP) wl[pos] = (bl << 9) | c;
          }
        }
  }
}

// ---------------- fixup: recompute flagged columns bitwise-np-exactly ----------------
// One thread per worklist entry: sequential-k fp32 fma (matches np/BLAS order,
// validated bitwise by round 1), full LIF chain, patch qs and kv.
__global__ __launch_bounds__(256) void k_fixup(
    const unsigned short* __restrict__ xs,
    const unsigned int* __restrict__ cnt, const unsigned int* __restrict__ wl,
    const float* __restrict__ qw, const float* __restrict__ qb,
    const float* __restrict__ qg, const float* __restrict__ qbe,
    const float* __restrict__ kw, const float* __restrict__ kb,
    const float* __restrict__ kg, const float* __restrict__ kbe,
    const float* __restrict__ vw, const float* __restrict__ vb,
    const float* __restrict__ vg, const float* __restrict__ vbe,
    unsigned short* __restrict__ qs, unsigned short* __restrict__ kv) {
  unsigned int n = *cnt;
  if (n > WL_CAP) n = WL_CAP;
  const float* W[3]  = {qw, kw, vw};
  const float* Bi[3] = {qb, kb, vb};
  const float* Gg[3] = {qg, kg, vg};
  const float* Be[3] = {qbe, kbe, vbe};
  for (unsigned int i = blockIdx.x * 256 + threadIdx.x; i < n; i += gridDim.x * 256) {
    const unsigned int e = wl[i];
    const int bl = e >> 9, col = e & 511;
    float sp3[3][4];
#pragma unroll
    for (int p = 0; p < 3; ++p) {
      float acc[4] = {0.f, 0.f, 0.f, 0.f};
      const float* w = W[p] + (size_t)col * Dd;
      const unsigned short* xcol = xs + (size_t)bl * Dd;
      for (int d = 0; d < Dd; ++d) {
        const float wv = w[d];
#pragma unroll
        for (int t = 0; t < 4; ++t) {
          const float a = xcol[(size_t)t * TSTRIDE + d] ? 1.0f : 0.0f;
          acc[t] = __fmaf_rn(a, wv, acc[t]);
        }
      }
      const float scl = __fmul_rn(INV_STD, Gg[p][col]);
      float m = 0.f, s = 0.f;
#pragma unroll
      for (int t = 0; t < 4; ++t) {
        const float y = __fadd_rn(__fmul_rn(__fadd_rn(acc[t], Bi[p][col]), scl), Be[p][col]);
        m = (t == 0) ? y : __fadd_rn(m * 0.25f * (1.0f - s), y);
        s = m > 0.5f ? 1.0f : 0.0f;
        sp3[p][t] = s;
      }
    }
#pragma unroll
    for (int t = 0; t < 4; ++t) {
      const size_t off = (size_t)t * TSTRIDE + (size_t)bl * Dd + col;
      qs[off] = sp3[0][t] > 0.f ? (unsigned short)0x3F80 : (unsigned short)0;
      kv[off] = (sp3[1][t] > 0.f && sp3[2][t] > 0.f) ? (unsigned short)0x3F80
                                                     : (unsigned short)0;
    }
  }
}

// ---------------- banded positional mixing + attn LIF (bf16 in/out) ----------------
__global__ __launch_bounds__(256) void k_attn_lif(const unsigned short* __restrict__ qs,
                                                  const unsigned short* __restrict__ kv,
                                                  const float* __restrict__ pb,
                                                  unsigned short* __restrict__ as_) {
  const int idx = blockIdx.x * 256 + threadIdx.x;  // 262144 threads, 8 ch each
  const int bi = idx >> 6;                         // 0..4095
  const int d0 = (idx & 63) << 3;
  const int i = bi & 1023;
  const int wmax = i < 7 ? i : 7;

  float pbv[8];
  const float* pr = pb + (size_t)i * 1024 + i;
  for (int w = 0; w <= wmax; ++w) pbv[w] = pr[-w];

  float pre[Tt][8];
#pragma unroll
  for (int t = 0; t < Tt; ++t) {
    float sum[8] = {0.f, 0.f, 0.f, 0.f, 0.f, 0.f, 0.f, 0.f};
    const size_t base = ((size_t)t * BL + bi) * Dd + d0;
    for (int w = wmax; w >= 0; --w) {  // ascending j order (matches np)
      uint4 raw = *(const uint4*)(kv + base - (size_t)w * Dd);
      float kvf[8];
      unpack8(raw, kvf);
#pragma unroll
      for (int c = 0; c < 8; ++c) sum[c] += pbv[w] * kvf[c];
    }
    uint4 qr = *(const uint4*)(qs + base);
    float qf[8];
    unpack8(qr, qf);
#pragma unroll
    for (int c = 0; c < 8; ++c) pre[t][c] = qf[c] * sum[c];
  }

  float m[8], s[8];
#pragma unroll
  for (int t = 0; t < Tt; ++t) {
    uint4 ow;
    unsigned short* owp = (unsigned short*)&ow;
#pragma unroll
    for (int c = 0; c < 8; ++c) {
      m[c] = (t == 0) ? pre[0][c] : m[c] * 0.25f * (1.0f - s[c]) + pre[t][c];
      s[c] = m[c] > 0.5f ? 1.0f : 0.0f;
      owp[c] = m[c] > 0.5f ? (unsigned short)0x3F80 : (unsigned short)0;
    }
    *(uint4*)(as_ + ((size_t)t * BL + bi) * Dd + d0) = ow;
  }
}

// ---------------- last GEMM (dual split) + BN, fp32 out ----------------
__global__ __launch_bounds__(256) void k_last_gemm(const unsigned short* __restrict__ A,
                                                   const unsigned short* __restrict__ Wsp,
                                                   const float* __restrict__ bias,
                                                   const float* __restrict__ gam,
                                                   const float* __restrict__ bet,
                                                   float* __restrict__ out) {
  __shared__ __align__(16) unsigned short Atile[128 * 32];
  __shared__ __align__(16) unsigned short Btile[2][128 * 32];
  const int tid = threadIdx.x;
  const int lane = tid & 63, wid = tid >> 6;
  const int quad = lane >> 4, lm = lane & 15;
  const int c0 = blockIdx.x * 128;
  const int m0 = blockIdx.y * 128;
  const int rr = tid >> 2;
  const int kc = (tid & 3) * 8;

  floatx4 acc[8][2];
#pragma unroll
  for (int mt = 0; mt < 8; ++mt)
#pragma unroll
    for (int nt = 0; nt < 2; ++nt) acc[mt][nt] = (floatx4)0.0f;

  for (int ks = 0; ks < 16; ++ks) {
    const int k0 = ks * 32;
    __syncthreads();
#pragma unroll
    for (int s = 0; s < 2; ++s)
      gl2lds16(A + ((size_t)(m0 + s * 64 + rr) * Dd + k0 + kc),
               &Atile[s * 2048 + tid * 8]);
#pragma unroll
    for (int sp = 0; sp < 2; ++sp)
#pragma unroll
      for (int s = 0; s < 2; ++s)
        gl2lds16(Wsp + (size_t)sp * WELEM + (size_t)(c0 + s * 64 + rr) * Dd + k0 + kc,
                 &Btile[sp][s * 2048 + tid * 8]);
    __syncthreads();
    short8 af[8];
#pragma unroll
    for (int mt = 0; mt < 8; ++mt)
      af[mt] = *(const short8*)&Atile[(mt * 16 + lm) * 32 + quad * 8];
#pragma unroll
    for (int nt = 0; nt < 2; ++nt) {
      const int nrow = wid * 32 + nt * 16 + lm;
#pragma unroll
      for (int sp = 0; sp < 2; ++sp) {
        short8 bfr = *(const short8*)&Btile[sp][nrow * 32 + quad * 8];
#pragma unroll
        for (int mt = 0; mt < 8; ++mt)
          acc[mt][nt] = __builtin_amdgcn_mfma_f32_16x16x32_bf16(af[mt], bfr, acc[mt][nt], 0, 0, 0);
      }
    }
  }

#pragma unroll
  for (int nt = 0; nt < 2; ++nt) {
    const int c = c0 + wid * 32 + nt * 16 + lm;
    const float scl = INV_STD * gam[c];
    const float sft = bias[c] * scl + bet[c];
#pragma unroll
    for (int mt = 0; mt < 8; ++mt)
#pragma unroll
      for (int r = 0; r < 4; ++r)
        out[(size_t)(m0 + mt * 16 + quad * 4 + r) * Dd + c] = acc[mt][nt][r] * scl + sft;
  }
}

extern "C" void kernel_launch(void* const* d_in, const int* in_sizes, int n_in,
                              void* d_out, int out_size, void* d_ws, size_t ws_size,
                              hipStream_t stream) {
  (void)in_sizes; (void)n_in; (void)out_size; (void)ws_size;
  const float* x        = (const float*)d_in[0];
  const float* pos_bias = (const float*)d_in[1];
  const float* q_w    = (const float*)d_in[2];
  const float* q_b    = (const float*)d_in[3];
  const float* q_g    = (const float*)d_in[4];
  const float* q_beta = (const float*)d_in[5];
  const float* k_w    = (const float*)d_in[6];
  const float* k_b    = (const float*)d_in[7];
  const float* k_g    = (const float*)d_in[8];
  const float* k_beta = (const float*)d_in[9];
  const float* v_w    = (const float*)d_in[10];
  const float* v_b    = (const float*)d_in[11];
  const float* v_g    = (const float*)d_in[12];
  const float* v_beta = (const float*)d_in[13];
  const float* last_w    = (const float*)d_in[14];
  const float* last_b    = (const float*)d_in[15];
  const float* last_g    = (const float*)d_in[16];
  const float* last_beta = (const float*)d_in[17];
  float* out = (float*)d_out;

  char* ws = (char*)d_ws;
  unsigned short* xs  = (unsigned short*)(ws + 0);
  unsigned short* qs  = (unsigned short*)(ws + 16777216);
  unsigned short* kv  = (unsigned short*)(ws + 33554432);
  unsigned short* as_ = (unsigned short*)(ws + 50331648);
  unsigned short* wsp = (unsigned short*)(ws + 67108864);
  unsigned short* wlast = wsp + (size_t)3 * 3 * WELEM;
  unsigned int* cnt = (unsigned int*)(ws + 73400320);
  unsigned int* wl  = (unsigned int*)(ws + 73400336);

  k_prep_w<<<WELEM / 256, 256, 0, stream>>>(q_w, k_w, v_w, last_w, wsp);
  k_lif_first<<<1024, 256, 0, stream>>>(x, xs, cnt);
  k_qkv_fused<<<dim3(4, 128), 256, 0, stream>>>(xs, wsp,
      k_b, k_g, k_beta, v_b, v_g, v_beta, q_b, q_g, q_beta, qs, kv, cnt, wl);
  k_fixup<<<128, 256, 0, stream>>>(xs, cnt, wl,
      q_w, q_b, q_g, q_beta, k_w, k_b, k_g, k_beta, v_w, v_b, v_g, v_beta, qs, kv);
  k_attn_lif<<<1024, 256, 0, stream>>>(qs, kv, pos_bias, as_);
  k_last_gemm<<<dim3(4, 128), 256, 0, stream>>>(as_, wlast,
      last_b, last_g, last_beta, out);
}